// Round 8
// baseline (569.759 us; speedup 1.0000x reference)
//
#include <hip/hip_runtime.h>
#include <cmath>

// GCN 2-layer forward on MI355X — round 8: XCD-sharded column slices.
// Tables stored slab-major (8 slabs x 16 cols for layer1, 8 x 8 cols for layer2).
// Aggregation blocks are (bucket, slice); blockIdx%8==slice rides the round-robin
// workgroup->XCD dispatch so each XCD gathers from a 3.2MB L2-resident slab.
// Pipeline: bcount -> bscan(+castW) -> bscatter -> bbuild ->
//           gemm1(x@W1, dinv-scaled, -> 8 slabs bf16) -> agg128s (sum+bias+relu -> h1 slabs) ->
//           gemm2(h1@W2, dinv-scaled, -> 8 slabs bf16) -> agg64s (-> fp32 slabs) -> lsm2.

#define THREADS 256
#define BSHIFT 8                      // 256 nodes per bucket
#define MAXB 512                      // >= ceil(N / 256)

__device__ __forceinline__ unsigned short f2bf(float f) {
    union { float f; unsigned u; } v; v.f = f;
    unsigned r = v.u + 0x7FFFu + ((v.u >> 16) & 1u);   // round-nearest-even
    return (unsigned short)(r >> 16);
}
__device__ __forceinline__ float bf_lo(unsigned u) {
    union { unsigned u; float f; } v; v.u = u << 16; return v.f;
}
__device__ __forceinline__ float bf_hi(unsigned u) {
    union { unsigned u; float f; } v; v.u = u & 0xFFFF0000u; return v.f;
}

// ---- bucket count: LDS histogram, flush once per block ----
__global__ __launch_bounds__(256) void k_bcount(const int* __restrict__ dst, int E, int B,
                                                int* __restrict__ bcnt) {
    __shared__ int lc[MAXB];
    for (int i = threadIdx.x; i < MAXB; i += 256) lc[i] = 0;
    __syncthreads();
    for (int e = blockIdx.x * blockDim.x + threadIdx.x; e < E; e += gridDim.x * blockDim.x)
        atomicAdd(&lc[dst[e] >> BSHIFT], 1);
    __syncthreads();
    for (int b = threadIdx.x; b < B; b += 256)
        if (lc[b]) atomicAdd(&bcnt[b], lc[b]);
}

// ---- block 0: exclusive scan of bcnt[B] -> boff[B+1]; blocks 1..: cast W -> bf16^T ----
__global__ __launch_bounds__(512) void k_bscan(const int* __restrict__ bcnt, int B,
                                               int* __restrict__ boff,
                                               const float* __restrict__ W1,
                                               const float* __restrict__ W2,
                                               unsigned short* __restrict__ Wt1,
                                               unsigned short* __restrict__ Wt2) {
    if (blockIdx.x == 0) {
        __shared__ int sh[MAXB];
        const int t = threadIdx.x;
        int v = (t < B) ? bcnt[t] : 0;
        sh[t] = v; __syncthreads();
        for (int o = 1; o < MAXB; o <<= 1) {
            int add = (t >= o) ? sh[t - o] : 0;
            __syncthreads();
            sh[t] += add;
            __syncthreads();
        }
        if (t < B) boff[t] = sh[t] - v;
        if (t == B - 1) boff[B] = sh[t];
    } else {
        int idx = (blockIdx.x - 1) * 512 + threadIdx.x;   // 0..24575
        if (idx < 16384) {
            int n = idx >> 7, k = idx & 127;
            Wt1[idx] = f2bf(W1[k * 128 + n]);
        } else if (idx < 16384 + 8192) {
            int t2 = idx - 16384;
            int n = t2 >> 7, k = t2 & 127;
            Wt2[t2] = f2bf(W2[k * 64 + n]);
        }
    }
}

// ---- scatter edges into bucket-contiguous packed records (loc<<24 | src) ----
__global__ __launch_bounds__(256) void k_bscatter(const int* __restrict__ src,
                                                  const int* __restrict__ dst, int E, int B,
                                                  const int* __restrict__ boff,
                                                  int* __restrict__ bfill,
                                                  unsigned* __restrict__ pairs) {
    __shared__ int lc[MAXB];
    __shared__ int lbase[MAXB];
    const int tid = threadIdx.x;
    const int e0 = blockIdx.x * 8192;
    for (int i = tid; i < MAXB; i += 256) lc[i] = 0;
    __syncthreads();
#pragma unroll
    for (int k = 0; k < 32; k++) {
        int e = e0 + k * 256 + tid;
        if (e < E) atomicAdd(&lc[dst[e] >> BSHIFT], 1);
    }
    __syncthreads();
    for (int b = tid; b < B; b += 256)
        lbase[b] = lc[b] ? atomicAdd(&bfill[b], lc[b]) : 0;
    __syncthreads();
    for (int i = tid; i < MAXB; i += 256) lc[i] = 0;
    __syncthreads();
#pragma unroll
    for (int k = 0; k < 32; k++) {
        int e = e0 + k * 256 + tid;
        if (e < E) {
            int s = src[e], d = dst[e];
            int b = d >> BSHIFT;
            int r = atomicAdd(&lc[b], 1);
            pairs[(size_t)boff[b] + lbase[b] + r] =
                ((unsigned)(d & 255) << 24) | (unsigned)s;   // src < 2^24
        }
    }
}

// ---- per-bucket CSR build: one block per bucket ----
__global__ __launch_bounds__(256) void k_bbuild(const unsigned* __restrict__ pairs,
                                                const int* __restrict__ boff, int N,
                                                int* __restrict__ deg,
                                                float* __restrict__ dinv,
                                                int* __restrict__ rowptr,
                                                int* __restrict__ csr_src) {
    __shared__ int ldeg[256], lex[256], lrank[256];
    const int b = blockIdx.x, tid = threadIdx.x;
    const int node0 = b << BSHIFT;
    const int base = boff[b];
    const int cnt_e = boff[b + 1] - base;
    ldeg[tid] = 0;
    __syncthreads();
    for (int e = tid; e < cnt_e; e += 256)
        atomicAdd(&ldeg[pairs[base + e] >> 24], 1);
    __syncthreads();
    int v = ldeg[tid];
    lex[tid] = v; __syncthreads();
    for (int o = 1; o < 256; o <<= 1) {
        int add = (tid >= o) ? lex[tid - o] : 0;
        __syncthreads();
        lex[tid] += add;
        __syncthreads();
    }
    int excl = lex[tid] - v;
    if (node0 + tid < N) {
        deg[node0 + tid] = v;
        dinv[node0 + tid] = rsqrtf((float)(v + 1));
        rowptr[node0 + tid] = base + excl;
    }
    __syncthreads();
    lex[tid] = excl;
    lrank[tid] = 0;
    __syncthreads();
    for (int e = tid; e < cnt_e; e += 256) {
        unsigned p = pairs[base + e];
        int loc = p >> 24;
        int r = atomicAdd(&lrank[loc], 1);
        csr_src[base + lex[loc] + r] = (int)(p & 0xFFFFFFu);
    }
}

typedef __attribute__((ext_vector_type(8))) short bf16x8;
typedef __attribute__((ext_vector_type(4))) float f32x4;

// Layer-1 GEMM: Out slabs[s][node][16 cols] (bf16) = dinv[row] * (x @ Wt1^T).
__global__ __launch_bounds__(256) void k_gemm1(const float* __restrict__ A,
                                               const unsigned short* __restrict__ Wt,
                                               const float* __restrict__ dinv,
                                               unsigned short* __restrict__ OutSlab,
                                               size_t SS, int M) {
    constexpr int KP = 136;
    __shared__ __align__(16) short As[64 * KP];
    __shared__ __align__(16) short Bs[128 * KP];
    const int tid = threadIdx.x;
    const int row0 = blockIdx.x * 64;

#pragma unroll
    for (int q = 0; q < 8; q++) {
        int f = tid + 256 * q;
        int r = f >> 5, c = (f & 31) * 4;
        float4 v = make_float4(0.f, 0.f, 0.f, 0.f);
        if (row0 + r < M) v = *(const float4*)&A[(size_t)(row0 + r) * 128 + c];
        ushort4 o;
        o.x = f2bf(v.x); o.y = f2bf(v.y); o.z = f2bf(v.z); o.w = f2bf(v.w);
        *(ushort4*)&As[r * KP + c] = o;
    }
    for (int f = tid; f < 128 * 16; f += 256) {
        int n = f >> 4, c = (f & 15) * 8;
        *(uint4*)&Bs[n * KP + c] = *(const uint4*)&Wt[n * 128 + c];
    }
    __syncthreads();

    const int wave = tid >> 6, lane = tid & 63;
    const int m = lane & 15, quad = lane >> 4;
    f32x4 acc[8] = {};
    const short* arow = &As[(16 * wave + m) * KP + quad * 8];
    const short* brow = &Bs[m * KP + quad * 8];
#pragma unroll
    for (int k0 = 0; k0 < 128; k0 += 32) {
        bf16x8 a = *(const bf16x8*)&arow[k0];
#pragma unroll
        for (int c = 0; c < 8; c++) {
            bf16x8 b = *(const bf16x8*)&brow[(size_t)c * 16 * KP + k0];
            acc[c] = __builtin_amdgcn_mfma_f32_16x16x32_bf16(a, b, acc[c], 0, 0, 0);
        }
    }

    float dv[4];
#pragma unroll
    for (int r = 0; r < 4; r++) {
        int row = row0 + 16 * wave + quad * 4 + r;
        dv[r] = dinv[row < M ? row : (M - 1)];
    }
    __syncthreads();
    short* Cs = As;                       // 64 x 128
#pragma unroll
    for (int c = 0; c < 8; c++)
#pragma unroll
        for (int r = 0; r < 4; r++)
            Cs[(16 * wave + quad * 4 + r) * 128 + 16 * c + m] = (short)f2bf(acc[c][r] * dv[r]);
    __syncthreads();
    // write slab-major: slab s <- cols [16s,16s+16)
#pragma unroll
    for (int q = 0; q < 4; q++) {
        int f = tid + 256 * q;            // 0..1023
        int s = f >> 7, idx = f & 127, r = idx >> 1, h = idx & 1;
        if (row0 + r < M)
            *(uint4*)&OutSlab[s * SS + (size_t)(row0 + r) * 16 + h * 8] =
                *(const uint4*)&Cs[r * 128 + s * 16 + h * 8];
    }
}

// Layer-2 GEMM: A from h1 slabs (8 x 16 cols bf16), Out slabs[s][node][8 cols].
__global__ __launch_bounds__(256) void k_gemm2(const unsigned short* __restrict__ ASlab,
                                               size_t SSA,
                                               const unsigned short* __restrict__ Wt,
                                               const float* __restrict__ dinv,
                                               unsigned short* __restrict__ OutSlab,
                                               size_t SSO, int M) {
    constexpr int KP = 136;
    __shared__ __align__(16) short As[64 * KP];
    __shared__ __align__(16) short Bs[64 * KP];
    const int tid = threadIdx.x;
    const int row0 = blockIdx.x * 64;

#pragma unroll
    for (int q = 0; q < 4; q++) {
        int f = tid + 256 * q;            // 0..1023
        int s = f >> 7, idx = f & 127, r = idx >> 1, h = idx & 1;
        uint4 v = make_uint4(0, 0, 0, 0);
        if (row0 + r < M)
            v = *(const uint4*)&ASlab[s * SSA + (size_t)(row0 + r) * 16 + h * 8];
        *(uint4*)&As[r * KP + s * 16 + h * 8] = v;
    }
    for (int f = tid; f < 64 * 16; f += 256) {
        int n = f >> 4, c = (f & 15) * 8;
        *(uint4*)&Bs[n * KP + c] = *(const uint4*)&Wt[n * 128 + c];
    }
    __syncthreads();

    const int wave = tid >> 6, lane = tid & 63;
    const int m = lane & 15, quad = lane >> 4;
    f32x4 acc[4] = {};
    const short* arow = &As[(16 * wave + m) * KP + quad * 8];
    const short* brow = &Bs[m * KP + quad * 8];
#pragma unroll
    for (int k0 = 0; k0 < 128; k0 += 32) {
        bf16x8 a = *(const bf16x8*)&arow[k0];
#pragma unroll
        for (int c = 0; c < 4; c++) {
            bf16x8 b = *(const bf16x8*)&brow[(size_t)c * 16 * KP + k0];
            acc[c] = __builtin_amdgcn_mfma_f32_16x16x32_bf16(a, b, acc[c], 0, 0, 0);
        }
    }

    float dv[4];
#pragma unroll
    for (int r = 0; r < 4; r++) {
        int row = row0 + 16 * wave + quad * 4 + r;
        dv[r] = dinv[row < M ? row : (M - 1)];
    }
    __syncthreads();
    short* Cs = As;                       // 64 x 64
#pragma unroll
    for (int c = 0; c < 4; c++)
#pragma unroll
        for (int r = 0; r < 4; r++)
            Cs[(16 * wave + quad * 4 + r) * 64 + 16 * c + m] = (short)f2bf(acc[c][r] * dv[r]);
    __syncthreads();
#pragma unroll
    for (int q = 0; q < 2; q++) {
        int f = tid + 256 * q;            // 0..511
        int s = f >> 6, r = f & 63;
        if (row0 + r < M)
            *(uint4*)&OutSlab[s * SSO + (size_t)(row0 + r) * 8] =
                *(const uint4*)&Cs[r * 64 + s * 8];
    }
}

// Sharded layer-1 aggregation: block = (bucket, slice); slice s gathers only from
// slab s (3.2MB, L2-resident on the XCD that blockIdx%8 lands on).
// Lane layout: 8 edge-slots x 8 col-pairs; shfl_xor(8/16/32) reduces slots.
__global__ __launch_bounds__(256) void k_agg128s(const int* __restrict__ csr_src,
                                                 const int* __restrict__ rowptr,
                                                 const int* __restrict__ deg,
                                                 const float* __restrict__ dinv,
                                                 const unsigned* __restrict__ xwSlab,
                                                 size_t SS32,
                                                 const float* __restrict__ bias,
                                                 unsigned* __restrict__ h1Slab, int N) {
    const int b = blockIdx.x >> 3, s = blockIdx.x & 7;
    const int wave = threadIdx.x >> 6, lane = threadIdx.x & 63;
    const int el = lane >> 3, c = lane & 7;
    const unsigned* slab = xwSlab + s * SS32;
    unsigned* oslab = h1Slab + s * SS32;
    const float2 bb = *(const float2*)&bias[s * 16 + 2 * c];
    for (int l = wave; l < 256; l += 4) {
        const int i = (b << BSHIFT) + l;
        if (i >= N) break;
        const int start = rowptr[i], cn = deg[i];
        const float di = dinv[i];
        float a0 = 0.f, a1 = 0.f;
        if (el == 0) {
            unsigned u = slab[(size_t)i * 8 + c];     // self row (pre-scaled by dinv[i])
            a0 = bf_lo(u); a1 = bf_hi(u);
        }
        for (int j = el; j < cn; j += 8) {
            int sr = csr_src[start + j];
            unsigned u = slab[(size_t)sr * 8 + c];
            a0 += bf_lo(u); a1 += bf_hi(u);
        }
        a0 += __shfl_xor(a0, 8);  a1 += __shfl_xor(a1, 8);
        a0 += __shfl_xor(a0, 16); a1 += __shfl_xor(a1, 16);
        a0 += __shfl_xor(a0, 32); a1 += __shfl_xor(a1, 32);
        if (lane < 8) {
            float r0 = fmaxf(di * a0 + bb.x, 0.f);    // bias + ReLU epilogue
            float r1 = fmaxf(di * a1 + bb.y, 0.f);
            oslab[(size_t)i * 8 + lane] = (unsigned)f2bf(r0) | ((unsigned)f2bf(r1) << 16);
        }
    }
}

// Sharded layer-2 aggregation: slice = 8 cols (4 uints). 16 edge-slots x 4 col-pairs.
// Writes fp32 slabs (bias folded); log_softmax runs in a final pass.
__global__ __launch_bounds__(256) void k_agg64s(const int* __restrict__ csr_src,
                                                const int* __restrict__ rowptr,
                                                const int* __restrict__ deg,
                                                const float* __restrict__ dinv,
                                                const unsigned* __restrict__ hwSlab,
                                                size_t SS32,
                                                const float* __restrict__ bias,
                                                float* __restrict__ outSlab,
                                                size_t SSO, int N) {
    const int b = blockIdx.x >> 3, s = blockIdx.x & 7;
    const int wave = threadIdx.x >> 6, lane = threadIdx.x & 63;
    const int el = lane >> 2, c = lane & 3;
    const unsigned* slab = hwSlab + s * SS32;
    float* oslab = outSlab + s * SSO;
    const float2 bb = *(const float2*)&bias[s * 8 + 2 * c];
    for (int l = wave; l < 256; l += 4) {
        const int i = (b << BSHIFT) + l;
        if (i >= N) break;
        const int start = rowptr[i], cn = deg[i];
        const float di = dinv[i];
        float a0 = 0.f, a1 = 0.f;
        if (el == 0) {
            unsigned u = slab[(size_t)i * 4 + c];
            a0 = bf_lo(u); a1 = bf_hi(u);
        }
        for (int j = el; j < cn; j += 16) {
            int sr = csr_src[start + j];
            unsigned u = slab[(size_t)sr * 4 + c];
            a0 += bf_lo(u); a1 += bf_hi(u);
        }
        a0 += __shfl_xor(a0, 4);  a1 += __shfl_xor(a1, 4);
        a0 += __shfl_xor(a0, 8);  a1 += __shfl_xor(a1, 8);
        a0 += __shfl_xor(a0, 16); a1 += __shfl_xor(a1, 16);
        a0 += __shfl_xor(a0, 32); a1 += __shfl_xor(a1, 32);
        if (lane < 4) {
            float v0 = di * a0 + bb.x;
            float v1 = di * a1 + bb.y;
            *(float2*)&oslab[(size_t)i * 8 + 2 * lane] = make_float2(v0, v1);
        }
    }
}

// Gather 8 fp32 slabs -> log_softmax over 64 cols -> d_out. One wave per node.
__global__ __launch_bounds__(256) void k_lsm2(const float* __restrict__ outSlab, size_t SSO,
                                              float* __restrict__ out, int N) {
    const int lane = threadIdx.x & 63;
    const int i = (blockIdx.x * blockDim.x + threadIdx.x) >> 6;
    if (i >= N) return;
    const int sl = lane >> 3, c = lane & 7;
    float v = outSlab[sl * SSO + (size_t)i * 8 + c];
    float m = v;
#pragma unroll
    for (int o = 32; o > 0; o >>= 1) m = fmaxf(m, __shfl_xor(m, o));
    float e = expf(v - m);
    float s = e;
#pragma unroll
    for (int o = 32; o > 0; o >>= 1) s += __shfl_xor(s, o);
    out[(size_t)i * 64 + sl * 8 + c] = v - m - logf(s);
}

extern "C" void kernel_launch(void* const* d_in, const int* in_sizes, int n_in,
                              void* d_out, int out_size, void* d_ws, size_t ws_size,
                              hipStream_t stream) {
    const float* x  = (const float*)d_in[0];
    const int*   ei = (const int*)d_in[1];
    const float* W1 = (const float*)d_in[2];
    const float* b1 = (const float*)d_in[3];
    const float* W2 = (const float*)d_in[4];
    const float* b2 = (const float*)d_in[5];

    const int N = in_sizes[0] / 128;   // 100000
    const int E = in_sizes[1] / 2;     // 1600000
    const int* src = ei;
    const int* dst = ei + E;
    const int B = (N + 255) >> BSHIFT; // 391 buckets

    const size_t SS128 = (size_t)N * 16;   // ushorts per 16-col slab
    const size_t SS128_32 = (size_t)N * 8; // uints per 16-col slab
    const size_t SS64 = (size_t)N * 8;     // ushorts per 8-col slab
    const size_t SS64_32 = (size_t)N * 4;  // uints per 8-col slab
    const size_t SSO = (size_t)N * 8;      // floats per 8-col fp32 slab

    char* ws = (char*)d_ws;
    size_t off = 0;
    auto alloc = [&](size_t bytes) {
        void* p = ws + off;
        off += (bytes + 255) & ~(size_t)255;
        return p;
    };
    int*            bcnt    = (int*)alloc(MAXB * 4 * 2);
    int*            bfill   = bcnt + MAXB;
    int*            boff    = (int*)alloc((MAXB + 1) * 4);
    int*            deg     = (int*)alloc((size_t)N * 4);
    float*          dinv    = (float*)alloc((size_t)N * 4);
    int*            rowptr  = (int*)alloc((size_t)N * 4);
    int*            csr_src = (int*)alloc((size_t)E * 4);
    unsigned*       pairs   = (unsigned*)alloc((size_t)E * 4);
    unsigned short* Wt1     = (unsigned short*)alloc(128 * 128 * 2);
    unsigned short* Wt2     = (unsigned short*)alloc(64 * 128 * 2);
    unsigned short* xw1     = (unsigned short*)alloc(8 * SS128 * 2);  // 8 slabs; reused as hw2
    unsigned short* h1      = (unsigned short*)alloc(8 * SS128 * 2);  // 8 slabs
    float*          otmp    = (float*)alloc(8 * SSO * 4);             // fp32 slabs pre-lsm
    unsigned short* hw2     = xw1;
    float*          out     = (float*)d_out;

    hipMemsetAsync(bcnt, 0, MAXB * 4 * 2, stream);

    // CSR build (bucketed) + weight cast
    k_bcount<<<512, THREADS, 0, stream>>>(dst, E, B, bcnt);
    k_bscan<<<49, 512, 0, stream>>>(bcnt, B, boff, W1, W2, Wt1, Wt2);
    k_bscatter<<<(E + 8191) / 8192, THREADS, 0, stream>>>(src, dst, E, B, boff, bfill, pairs);
    k_bbuild<<<B, THREADS, 0, stream>>>(pairs, boff, N, deg, dinv, rowptr, csr_src);

    // Layer 1
    k_gemm1<<<(N + 63) / 64, THREADS, 0, stream>>>(x, Wt1, dinv, xw1, SS128, N);
    k_agg128s<<<B * 8, THREADS, 0, stream>>>(csr_src, rowptr, deg, dinv,
                                             (const unsigned*)xw1, SS128_32, b1,
                                             (unsigned*)h1, N);

    // Layer 2
    k_gemm2<<<(N + 63) / 64, THREADS, 0, stream>>>(h1, SS128, Wt2, dinv, hw2, SS64, N);
    k_agg64s<<<B * 8, THREADS, 0, stream>>>(csr_src, rowptr, deg, dinv,
                                            (const unsigned*)hw2, SS64_32, b2, otmp, SSO, N);

    // log_softmax (gathers the 8 fp32 slabs)
    k_lsm2<<<(N * 64 + THREADS - 1) / THREADS, THREADS, 0, stream>>>(otmp, SSO, out, N);
}

// Round 9
// 382.777 us; speedup vs baseline: 1.4885x; 1.4885x over previous
//
#include <hip/hip_runtime.h>
#include <cmath>

// GCN 2-layer forward on MI355X — round 9: XCD-sharded slabs (kept: FETCH 204->54MB)
// with MLP-restored aggregation: one 8-lane group per node, 8 nodes/wave, no shuffles,
// unroll-4 edge walks -> 32 independent L2-hit gathers in flight per wave.
// Pipeline: bcount -> bscan(+castW) -> bscatter -> bbuild ->
//           gemm1(x@W1, dinv-scaled, -> 8 slabs bf16) -> agg128s -> 
//           gemm2(h1@W2, dinv-scaled, -> 8 slabs bf16) -> agg64s -> lsm2.

#define THREADS 256
#define BSHIFT 8                      // 256 nodes per bucket
#define MAXB 512                      // >= ceil(N / 256)

__device__ __forceinline__ unsigned short f2bf(float f) {
    union { float f; unsigned u; } v; v.f = f;
    unsigned r = v.u + 0x7FFFu + ((v.u >> 16) & 1u);   // round-nearest-even
    return (unsigned short)(r >> 16);
}
__device__ __forceinline__ float bf_lo(unsigned u) {
    union { unsigned u; float f; } v; v.u = u << 16; return v.f;
}
__device__ __forceinline__ float bf_hi(unsigned u) {
    union { unsigned u; float f; } v; v.u = u & 0xFFFF0000u; return v.f;
}

// ---- bucket count: LDS histogram, flush once per block ----
__global__ __launch_bounds__(256) void k_bcount(const int* __restrict__ dst, int E, int B,
                                                int* __restrict__ bcnt) {
    __shared__ int lc[MAXB];
    for (int i = threadIdx.x; i < MAXB; i += 256) lc[i] = 0;
    __syncthreads();
    for (int e = blockIdx.x * blockDim.x + threadIdx.x; e < E; e += gridDim.x * blockDim.x)
        atomicAdd(&lc[dst[e] >> BSHIFT], 1);
    __syncthreads();
    for (int b = threadIdx.x; b < B; b += 256)
        if (lc[b]) atomicAdd(&bcnt[b], lc[b]);
}

// ---- block 0: exclusive scan of bcnt[B] -> boff[B+1]; blocks 1..: cast W -> bf16^T ----
__global__ __launch_bounds__(512) void k_bscan(const int* __restrict__ bcnt, int B,
                                               int* __restrict__ boff,
                                               const float* __restrict__ W1,
                                               const float* __restrict__ W2,
                                               unsigned short* __restrict__ Wt1,
                                               unsigned short* __restrict__ Wt2) {
    if (blockIdx.x == 0) {
        __shared__ int sh[MAXB];
        const int t = threadIdx.x;
        int v = (t < B) ? bcnt[t] : 0;
        sh[t] = v; __syncthreads();
        for (int o = 1; o < MAXB; o <<= 1) {
            int add = (t >= o) ? sh[t - o] : 0;
            __syncthreads();
            sh[t] += add;
            __syncthreads();
        }
        if (t < B) boff[t] = sh[t] - v;
        if (t == B - 1) boff[B] = sh[t];
    } else {
        int idx = (blockIdx.x - 1) * 512 + threadIdx.x;   // 0..24575
        if (idx < 16384) {
            int n = idx >> 7, k = idx & 127;
            Wt1[idx] = f2bf(W1[k * 128 + n]);
        } else if (idx < 16384 + 8192) {
            int t2 = idx - 16384;
            int n = t2 >> 7, k = t2 & 127;
            Wt2[t2] = f2bf(W2[k * 64 + n]);
        }
    }
}

// ---- scatter edges into bucket-contiguous packed records (loc<<24 | src) ----
__global__ __launch_bounds__(256) void k_bscatter(const int* __restrict__ src,
                                                  const int* __restrict__ dst, int E, int B,
                                                  const int* __restrict__ boff,
                                                  int* __restrict__ bfill,
                                                  unsigned* __restrict__ pairs) {
    __shared__ int lc[MAXB];
    __shared__ int lbase[MAXB];
    const int tid = threadIdx.x;
    const int e0 = blockIdx.x * 8192;
    for (int i = tid; i < MAXB; i += 256) lc[i] = 0;
    __syncthreads();
#pragma unroll
    for (int k = 0; k < 32; k++) {
        int e = e0 + k * 256 + tid;
        if (e < E) atomicAdd(&lc[dst[e] >> BSHIFT], 1);
    }
    __syncthreads();
    for (int b = tid; b < B; b += 256)
        lbase[b] = lc[b] ? atomicAdd(&bfill[b], lc[b]) : 0;
    __syncthreads();
    for (int i = tid; i < MAXB; i += 256) lc[i] = 0;
    __syncthreads();
#pragma unroll
    for (int k = 0; k < 32; k++) {
        int e = e0 + k * 256 + tid;
        if (e < E) {
            int s = src[e], d = dst[e];
            int b = d >> BSHIFT;
            int r = atomicAdd(&lc[b], 1);
            pairs[(size_t)boff[b] + lbase[b] + r] =
                ((unsigned)(d & 255) << 24) | (unsigned)s;   // src < 2^24
        }
    }
}

// ---- per-bucket CSR build: one block per bucket ----
__global__ __launch_bounds__(256) void k_bbuild(const unsigned* __restrict__ pairs,
                                                const int* __restrict__ boff, int N,
                                                int* __restrict__ deg,
                                                float* __restrict__ dinv,
                                                int* __restrict__ rowptr,
                                                int* __restrict__ csr_src) {
    __shared__ int ldeg[256], lex[256], lrank[256];
    const int b = blockIdx.x, tid = threadIdx.x;
    const int node0 = b << BSHIFT;
    const int base = boff[b];
    const int cnt_e = boff[b + 1] - base;
    ldeg[tid] = 0;
    __syncthreads();
    for (int e = tid; e < cnt_e; e += 256)
        atomicAdd(&ldeg[pairs[base + e] >> 24], 1);
    __syncthreads();
    int v = ldeg[tid];
    lex[tid] = v; __syncthreads();
    for (int o = 1; o < 256; o <<= 1) {
        int add = (tid >= o) ? lex[tid - o] : 0;
        __syncthreads();
        lex[tid] += add;
        __syncthreads();
    }
    int excl = lex[tid] - v;
    if (node0 + tid < N) {
        deg[node0 + tid] = v;
        dinv[node0 + tid] = rsqrtf((float)(v + 1));
        rowptr[node0 + tid] = base + excl;
    }
    __syncthreads();
    lex[tid] = excl;
    lrank[tid] = 0;
    __syncthreads();
    for (int e = tid; e < cnt_e; e += 256) {
        unsigned p = pairs[base + e];
        int loc = p >> 24;
        int r = atomicAdd(&lrank[loc], 1);
        csr_src[base + lex[loc] + r] = (int)(p & 0xFFFFFFu);
    }
}

typedef __attribute__((ext_vector_type(8))) short bf16x8;
typedef __attribute__((ext_vector_type(4))) float f32x4;

// Layer-1 GEMM: Out slabs[s][node][16 cols] (bf16) = dinv[row] * (x @ Wt1^T).
__global__ __launch_bounds__(256) void k_gemm1(const float* __restrict__ A,
                                               const unsigned short* __restrict__ Wt,
                                               const float* __restrict__ dinv,
                                               unsigned short* __restrict__ OutSlab,
                                               size_t SS, int M) {
    constexpr int KP = 136;
    __shared__ __align__(16) short As[64 * KP];
    __shared__ __align__(16) short Bs[128 * KP];
    const int tid = threadIdx.x;
    const int row0 = blockIdx.x * 64;

#pragma unroll
    for (int q = 0; q < 8; q++) {
        int f = tid + 256 * q;
        int r = f >> 5, c = (f & 31) * 4;
        float4 v = make_float4(0.f, 0.f, 0.f, 0.f);
        if (row0 + r < M) v = *(const float4*)&A[(size_t)(row0 + r) * 128 + c];
        ushort4 o;
        o.x = f2bf(v.x); o.y = f2bf(v.y); o.z = f2bf(v.z); o.w = f2bf(v.w);
        *(ushort4*)&As[r * KP + c] = o;
    }
    for (int f = tid; f < 128 * 16; f += 256) {
        int n = f >> 4, c = (f & 15) * 8;
        *(uint4*)&Bs[n * KP + c] = *(const uint4*)&Wt[n * 128 + c];
    }
    __syncthreads();

    const int wave = tid >> 6, lane = tid & 63;
    const int m = lane & 15, quad = lane >> 4;
    f32x4 acc[8] = {};
    const short* arow = &As[(16 * wave + m) * KP + quad * 8];
    const short* brow = &Bs[m * KP + quad * 8];
#pragma unroll
    for (int k0 = 0; k0 < 128; k0 += 32) {
        bf16x8 a = *(const bf16x8*)&arow[k0];
#pragma unroll
        for (int c = 0; c < 8; c++) {
            bf16x8 b = *(const bf16x8*)&brow[(size_t)c * 16 * KP + k0];
            acc[c] = __builtin_amdgcn_mfma_f32_16x16x32_bf16(a, b, acc[c], 0, 0, 0);
        }
    }

    float dv[4];
#pragma unroll
    for (int r = 0; r < 4; r++) {
        int row = row0 + 16 * wave + quad * 4 + r;
        dv[r] = dinv[row < M ? row : (M - 1)];
    }
    __syncthreads();
    short* Cs = As;                       // 64 x 128
#pragma unroll
    for (int c = 0; c < 8; c++)
#pragma unroll
        for (int r = 0; r < 4; r++)
            Cs[(16 * wave + quad * 4 + r) * 128 + 16 * c + m] = (short)f2bf(acc[c][r] * dv[r]);
    __syncthreads();
    // write slab-major: slab s <- cols [16s,16s+16)
#pragma unroll
    for (int q = 0; q < 4; q++) {
        int f = tid + 256 * q;            // 0..1023
        int s = f >> 7, idx = f & 127, r = idx >> 1, h = idx & 1;
        if (row0 + r < M)
            *(uint4*)&OutSlab[s * SS + (size_t)(row0 + r) * 16 + h * 8] =
                *(const uint4*)&Cs[r * 128 + s * 16 + h * 8];
    }
}

// Layer-2 GEMM: A from h1 slabs (8 x 16 cols bf16), Out slabs[s][node][8 cols].
__global__ __launch_bounds__(256) void k_gemm2(const unsigned short* __restrict__ ASlab,
                                               size_t SSA,
                                               const unsigned short* __restrict__ Wt,
                                               const float* __restrict__ dinv,
                                               unsigned short* __restrict__ OutSlab,
                                               size_t SSO, int M) {
    constexpr int KP = 136;
    __shared__ __align__(16) short As[64 * KP];
    __shared__ __align__(16) short Bs[64 * KP];
    const int tid = threadIdx.x;
    const int row0 = blockIdx.x * 64;

#pragma unroll
    for (int q = 0; q < 4; q++) {
        int f = tid + 256 * q;            // 0..1023
        int s = f >> 7, idx = f & 127, r = idx >> 1, h = idx & 1;
        uint4 v = make_uint4(0, 0, 0, 0);
        if (row0 + r < M)
            v = *(const uint4*)&ASlab[s * SSA + (size_t)(row0 + r) * 16 + h * 8];
        *(uint4*)&As[r * KP + s * 16 + h * 8] = v;
    }
    for (int f = tid; f < 64 * 16; f += 256) {
        int n = f >> 4, c = (f & 15) * 8;
        *(uint4*)&Bs[n * KP + c] = *(const uint4*)&Wt[n * 128 + c];
    }
    __syncthreads();

    const int wave = tid >> 6, lane = tid & 63;
    const int m = lane & 15, quad = lane >> 4;
    f32x4 acc[4] = {};
    const short* arow = &As[(16 * wave + m) * KP + quad * 8];
    const short* brow = &Bs[m * KP + quad * 8];
#pragma unroll
    for (int k0 = 0; k0 < 128; k0 += 32) {
        bf16x8 a = *(const bf16x8*)&arow[k0];
#pragma unroll
        for (int c = 0; c < 4; c++) {
            bf16x8 b = *(const bf16x8*)&brow[(size_t)c * 16 * KP + k0];
            acc[c] = __builtin_amdgcn_mfma_f32_16x16x32_bf16(a, b, acc[c], 0, 0, 0);
        }
    }

    float dv[4];
#pragma unroll
    for (int r = 0; r < 4; r++) {
        int row = row0 + 16 * wave + quad * 4 + r;
        dv[r] = dinv[row < M ? row : (M - 1)];
    }
    __syncthreads();
    short* Cs = As;                       // 64 x 64
#pragma unroll
    for (int c = 0; c < 4; c++)
#pragma unroll
        for (int r = 0; r < 4; r++)
            Cs[(16 * wave + quad * 4 + r) * 64 + 16 * c + m] = (short)f2bf(acc[c][r] * dv[r]);
    __syncthreads();
#pragma unroll
    for (int q = 0; q < 2; q++) {
        int f = tid + 256 * q;            // 0..511
        int s = f >> 6, r = f & 63;
        if (row0 + r < M)
            *(uint4*)&OutSlab[s * SSO + (size_t)(row0 + r) * 8] =
                *(const uint4*)&Cs[r * 64 + s * 8];
    }
}

// Sharded layer-1 aggregation, MLP-restored: one 8-lane group per node, 8 nodes/wave,
// each group walks its own edge list (unroll-4) -> 32 independent gathers in flight.
// No cross-lane reduction; stores are wave-contiguous 256B.
__global__ __launch_bounds__(256) void k_agg128s(const int* __restrict__ csr_src,
                                                 const int* __restrict__ rowptr,
                                                 const int* __restrict__ deg,
                                                 const float* __restrict__ dinv,
                                                 const unsigned* __restrict__ xwSlab,
                                                 size_t SS32,
                                                 const float* __restrict__ bias,
                                                 unsigned* __restrict__ h1Slab, int N) {
    const int b = blockIdx.x >> 3, s = blockIdx.x & 7;
    const int wave = threadIdx.x >> 6, lane = threadIdx.x & 63;
    const int g = lane >> 3, c = lane & 7;      // node-group, column
    const unsigned* slab = xwSlab + s * SS32;
    unsigned* oslab = h1Slab + s * SS32;
    const float2 bb = *(const float2*)&bias[s * 16 + 2 * c];
    const int node0 = b << BSHIFT;
    for (int l = wave * 8; l < 256; l += 32) {
        const int i = node0 + l + g;
        const bool valid = i < N;
        const int start = valid ? rowptr[i] : 0;
        const int cn = valid ? deg[i] : 0;
        const float di = valid ? dinv[i] : 0.f;
        unsigned u = valid ? slab[(size_t)i * 8 + c] : 0u;   // self row (pre-scaled)
        float a0 = bf_lo(u), a1 = bf_hi(u);
        int j = 0;
        for (; j + 4 <= cn; j += 4) {
            int s0 = csr_src[start + j];
            int s1 = csr_src[start + j + 1];
            int s2 = csr_src[start + j + 2];
            int s3 = csr_src[start + j + 3];
            unsigned u0 = slab[(size_t)s0 * 8 + c];
            unsigned u1 = slab[(size_t)s1 * 8 + c];
            unsigned u2 = slab[(size_t)s2 * 8 + c];
            unsigned u3 = slab[(size_t)s3 * 8 + c];
            a0 += bf_lo(u0) + bf_lo(u1) + bf_lo(u2) + bf_lo(u3);
            a1 += bf_hi(u0) + bf_hi(u1) + bf_hi(u2) + bf_hi(u3);
        }
        for (; j < cn; j++) {
            int s0 = csr_src[start + j];
            unsigned u0 = slab[(size_t)s0 * 8 + c];
            a0 += bf_lo(u0); a1 += bf_hi(u0);
        }
        if (valid) {
            float r0 = fmaxf(di * a0 + bb.x, 0.f);   // bias + ReLU epilogue
            float r1 = fmaxf(di * a1 + bb.y, 0.f);
            oslab[(size_t)i * 8 + c] = (unsigned)f2bf(r0) | ((unsigned)f2bf(r1) << 16);
        }
    }
}

// Sharded layer-2 aggregation: 4-lane group per node, 16 nodes/wave, unroll-4
// -> 64 independent gathers in flight. Writes fp32 slabs (bias folded).
__global__ __launch_bounds__(256) void k_agg64s(const int* __restrict__ csr_src,
                                                const int* __restrict__ rowptr,
                                                const int* __restrict__ deg,
                                                const float* __restrict__ dinv,
                                                const unsigned* __restrict__ hwSlab,
                                                size_t SS32,
                                                const float* __restrict__ bias,
                                                float* __restrict__ outSlab,
                                                size_t SSO, int N) {
    const int b = blockIdx.x >> 3, s = blockIdx.x & 7;
    const int wave = threadIdx.x >> 6, lane = threadIdx.x & 63;
    const int g = lane >> 2, c = lane & 3;      // node-group, column
    const unsigned* slab = hwSlab + s * SS32;
    float* oslab = outSlab + s * SSO;
    const float2 bb = *(const float2*)&bias[s * 8 + 2 * c];
    const int node0 = b << BSHIFT;
    for (int l = wave * 16; l < 256; l += 64) {
        const int i = node0 + l + g;
        const bool valid = i < N;
        const int start = valid ? rowptr[i] : 0;
        const int cn = valid ? deg[i] : 0;
        const float di = valid ? dinv[i] : 0.f;
        unsigned u = valid ? slab[(size_t)i * 4 + c] : 0u;   // self row (pre-scaled)
        float a0 = bf_lo(u), a1 = bf_hi(u);
        int j = 0;
        for (; j + 4 <= cn; j += 4) {
            int s0 = csr_src[start + j];
            int s1 = csr_src[start + j + 1];
            int s2 = csr_src[start + j + 2];
            int s3 = csr_src[start + j + 3];
            unsigned u0 = slab[(size_t)s0 * 4 + c];
            unsigned u1 = slab[(size_t)s1 * 4 + c];
            unsigned u2 = slab[(size_t)s2 * 4 + c];
            unsigned u3 = slab[(size_t)s3 * 4 + c];
            a0 += bf_lo(u0) + bf_lo(u1) + bf_lo(u2) + bf_lo(u3);
            a1 += bf_hi(u0) + bf_hi(u1) + bf_hi(u2) + bf_hi(u3);
        }
        for (; j < cn; j++) {
            int s0 = csr_src[start + j];
            unsigned u0 = slab[(size_t)s0 * 4 + c];
            a0 += bf_lo(u0); a1 += bf_hi(u0);
        }
        if (valid) {
            float v0 = di * a0 + bb.x;
            float v1 = di * a1 + bb.y;
            *(float2*)&oslab[(size_t)i * 8 + 2 * c] = make_float2(v0, v1);
        }
    }
}

// Gather 8 fp32 slabs -> log_softmax over 64 cols -> d_out. One wave per node.
__global__ __launch_bounds__(256) void k_lsm2(const float* __restrict__ outSlab, size_t SSO,
                                              float* __restrict__ out, int N) {
    const int lane = threadIdx.x & 63;
    const int i = (blockIdx.x * blockDim.x + threadIdx.x) >> 6;
    if (i >= N) return;
    const int sl = lane >> 3, c = lane & 7;
    float v = outSlab[sl * SSO + (size_t)i * 8 + c];
    float m = v;
#pragma unroll
    for (int o = 32; o > 0; o >>= 1) m = fmaxf(m, __shfl_xor(m, o));
    float e = expf(v - m);
    float s = e;
#pragma unroll
    for (int o = 32; o > 0; o >>= 1) s += __shfl_xor(s, o);
    out[(size_t)i * 64 + sl * 8 + c] = v - m - logf(s);
}

extern "C" void kernel_launch(void* const* d_in, const int* in_sizes, int n_in,
                              void* d_out, int out_size, void* d_ws, size_t ws_size,
                              hipStream_t stream) {
    const float* x  = (const float*)d_in[0];
    const int*   ei = (const int*)d_in[1];
    const float* W1 = (const float*)d_in[2];
    const float* b1 = (const float*)d_in[3];
    const float* W2 = (const float*)d_in[4];
    const float* b2 = (const float*)d_in[5];

    const int N = in_sizes[0] / 128;   // 100000
    const int E = in_sizes[1] / 2;     // 1600000
    const int* src = ei;
    const int* dst = ei + E;
    const int B = (N + 255) >> BSHIFT; // 391 buckets

    const size_t SS128 = (size_t)N * 16;   // ushorts per 16-col slab
    const size_t SS128_32 = (size_t)N * 8; // uints per 16-col slab
    const size_t SS64 = (size_t)N * 8;     // ushorts per 8-col slab
    const size_t SS64_32 = (size_t)N * 4;  // uints per 8-col slab
    const size_t SSO = (size_t)N * 8;      // floats per 8-col fp32 slab

    char* ws = (char*)d_ws;
    size_t off = 0;
    auto alloc = [&](size_t bytes) {
        void* p = ws + off;
        off += (bytes + 255) & ~(size_t)255;
        return p;
    };
    int*            bcnt    = (int*)alloc(MAXB * 4 * 2);
    int*            bfill   = bcnt + MAXB;
    int*            boff    = (int*)alloc((MAXB + 1) * 4);
    int*            deg     = (int*)alloc((size_t)N * 4);
    float*          dinv    = (float*)alloc((size_t)N * 4);
    int*            rowptr  = (int*)alloc((size_t)N * 4);
    int*            csr_src = (int*)alloc((size_t)E * 4);
    unsigned*       pairs   = (unsigned*)alloc((size_t)E * 4);
    unsigned short* Wt1     = (unsigned short*)alloc(128 * 128 * 2);
    unsigned short* Wt2     = (unsigned short*)alloc(64 * 128 * 2);
    unsigned short* xw1     = (unsigned short*)alloc(8 * SS128 * 2);  // 8 slabs; reused as hw2
    unsigned short* h1      = (unsigned short*)alloc(8 * SS128 * 2);  // 8 slabs
    float*          otmp    = (float*)alloc(8 * SSO * 4);             // fp32 slabs pre-lsm
    unsigned short* hw2     = xw1;
    float*          out     = (float*)d_out;

    hipMemsetAsync(bcnt, 0, MAXB * 4 * 2, stream);

    // CSR build (bucketed) + weight cast
    k_bcount<<<512, THREADS, 0, stream>>>(dst, E, B, bcnt);
    k_bscan<<<49, 512, 0, stream>>>(bcnt, B, boff, W1, W2, Wt1, Wt2);
    k_bscatter<<<(E + 8191) / 8192, THREADS, 0, stream>>>(src, dst, E, B, boff, bfill, pairs);
    k_bbuild<<<B, THREADS, 0, stream>>>(pairs, boff, N, deg, dinv, rowptr, csr_src);

    // Layer 1
    k_gemm1<<<(N + 63) / 64, THREADS, 0, stream>>>(x, Wt1, dinv, xw1, SS128, N);
    k_agg128s<<<B * 8, THREADS, 0, stream>>>(csr_src, rowptr, deg, dinv,
                                             (const unsigned*)xw1, SS128_32, b1,
                                             (unsigned*)h1, N);

    // Layer 2
    k_gemm2<<<(N + 63) / 64, THREADS, 0, stream>>>(h1, SS128, Wt2, dinv, hw2, SS64, N);
    k_agg64s<<<B * 8, THREADS, 0, stream>>>(csr_src, rowptr, deg, dinv,
                                            (const unsigned*)hw2, SS64_32, b2, otmp, SSO, N);

    // log_softmax (gathers the 8 fp32 slabs)
    k_lsm2<<<(N * 64 + THREADS - 1) / THREADS, THREADS, 0, stream>>>(otmp, SSO, out, N);
}

// Round 10
// 333.754 us; speedup vs baseline: 1.7071x; 1.1469x over previous
//
#include <hip/hip_runtime.h>
#include <cmath>

// GCN 2-layer forward on MI355X — round 10: row-major aggregation (sharding abandoned:
// r8/r9 showed request-width vs locality tradeoff nets worse than plain row-major),
// atomic-free memset-free CSR build, 8 dispatches total.
// Pipeline: bcount(partial hists) -> bscan(boff+coff, +castW) -> bscatter(no atomics) ->
//           bbuild -> gemm1(x@W1, dinv-scaled bf16) -> agg128(sum+bias+relu -> bf16) ->
//           gemm2(h1@W2, dinv-scaled bf16) -> agg64(half-wave/node + fused log_softmax).

#define THREADS 256
#define BSHIFT 8                      // 256 nodes per bucket
#define MAXB 512                      // >= ceil(N / 256)
#define CHUNK 8192                    // edges per bcount/bscatter block

__device__ __forceinline__ unsigned short f2bf(float f) {
    union { float f; unsigned u; } v; v.f = f;
    unsigned r = v.u + 0x7FFFu + ((v.u >> 16) & 1u);   // round-nearest-even
    return (unsigned short)(r >> 16);
}
__device__ __forceinline__ float bf_lo(unsigned u) {
    union { unsigned u; float f; } v; v.u = u << 16; return v.f;
}
__device__ __forceinline__ float bf_hi(unsigned u) {
    union { unsigned u; float f; } v; v.u = u & 0xFFFF0000u; return v.f;
}

// ---- per-chunk bucket histograms: pcnt[w*MAXB + b] (no global atomics, no memset) ----
__global__ __launch_bounds__(256) void k_bcount(const int* __restrict__ dst, int E,
                                                int* __restrict__ pcnt) {
    __shared__ int lc[MAXB];
    const int w = blockIdx.x, tid = threadIdx.x;
    for (int i = tid; i < MAXB; i += 256) lc[i] = 0;
    __syncthreads();
    const int e0 = w * CHUNK;
#pragma unroll
    for (int k = 0; k < CHUNK / 256; k++) {
        int e = e0 + k * 256 + tid;
        if (e < E) atomicAdd(&lc[dst[e] >> BSHIFT], 1);
    }
    __syncthreads();
    for (int b = tid; b < MAXB; b += 256) pcnt[w * MAXB + b] = lc[b];
}

// ---- block 0: column-scan pcnt -> per-block bases coff + bucket offsets boff.
//      blocks 1..48: cast W1/W2 -> bf16 transposed. ----
__global__ __launch_bounds__(512) void k_bscan(const int* __restrict__ pcnt, int W,
                                               int* __restrict__ coff,
                                               int* __restrict__ boff,
                                               const float* __restrict__ W1,
                                               const float* __restrict__ W2,
                                               unsigned short* __restrict__ Wt1,
                                               unsigned short* __restrict__ Wt2) {
    if (blockIdx.x == 0) {
        __shared__ int sh[MAXB];
        const int b = threadIdx.x;           // 512 threads, one per bucket
        int acc = 0;
        for (int w = 0; w < W; w++) {        // coalesced row-wise
            coff[w * MAXB + b] = acc;
            acc += pcnt[w * MAXB + b];
        }
        sh[b] = acc; __syncthreads();
        for (int o = 1; o < MAXB; o <<= 1) {
            int add = (b >= o) ? sh[b - o] : 0;
            __syncthreads();
            sh[b] += add;
            __syncthreads();
        }
        boff[b] = sh[b] - acc;               // exclusive
        if (b == MAXB - 1) boff[MAXB] = sh[b];
    } else {
        int idx = (blockIdx.x - 1) * 512 + threadIdx.x;   // 0..24575
        if (idx < 16384) {
            int n = idx >> 7, k = idx & 127;
            Wt1[idx] = f2bf(W1[k * 128 + n]);
        } else if (idx < 16384 + 8192) {
            int t2 = idx - 16384;
            int n = t2 >> 7, k = t2 & 127;
            Wt2[t2] = f2bf(W2[k * 64 + n]);
        }
    }
}

// ---- scatter edges into bucket-contiguous packed records; fully deterministic,
//      no global atomics: base = boff[b] + coff[w][b], rank via LDS. ----
__global__ __launch_bounds__(256) void k_bscatter(const int* __restrict__ src,
                                                  const int* __restrict__ dst, int E,
                                                  const int* __restrict__ boff,
                                                  const int* __restrict__ coff,
                                                  unsigned* __restrict__ pairs) {
    __shared__ int lbase[MAXB];
    __shared__ int lc[MAXB];
    const int w = blockIdx.x, tid = threadIdx.x;
    for (int b = tid; b < MAXB; b += 256) {
        lbase[b] = boff[b] + coff[w * MAXB + b];
        lc[b] = 0;
    }
    __syncthreads();
    const int e0 = w * CHUNK;
#pragma unroll
    for (int k = 0; k < CHUNK / 256; k++) {
        int e = e0 + k * 256 + tid;
        if (e < E) {
            int s = src[e], d = dst[e];
            int b = d >> BSHIFT;
            int r = atomicAdd(&lc[b], 1);
            pairs[(size_t)lbase[b] + r] =
                ((unsigned)(d & 255) << 24) | (unsigned)s;   // src < 2^24
        }
    }
}

// ---- per-bucket CSR build: one block per bucket ----
__global__ __launch_bounds__(256) void k_bbuild(const unsigned* __restrict__ pairs,
                                                const int* __restrict__ boff, int N,
                                                int* __restrict__ deg,
                                                float* __restrict__ dinv,
                                                int* __restrict__ rowptr,
                                                int* __restrict__ csr_src) {
    __shared__ int ldeg[256], lex[256], lrank[256];
    const int b = blockIdx.x, tid = threadIdx.x;
    const int node0 = b << BSHIFT;
    const int base = boff[b];
    const int cnt_e = boff[b + 1] - base;
    ldeg[tid] = 0;
    __syncthreads();
    for (int e = tid; e < cnt_e; e += 256)
        atomicAdd(&ldeg[pairs[base + e] >> 24], 1);
    __syncthreads();
    int v = ldeg[tid];
    lex[tid] = v; __syncthreads();
    for (int o = 1; o < 256; o <<= 1) {
        int add = (tid >= o) ? lex[tid - o] : 0;
        __syncthreads();
        lex[tid] += add;
        __syncthreads();
    }
    int excl = lex[tid] - v;
    if (node0 + tid < N) {
        deg[node0 + tid] = v;
        dinv[node0 + tid] = rsqrtf((float)(v + 1));
        rowptr[node0 + tid] = base + excl;
    }
    __syncthreads();
    lex[tid] = excl;
    lrank[tid] = 0;
    __syncthreads();
    for (int e = tid; e < cnt_e; e += 256) {
        unsigned p = pairs[base + e];
        int loc = p >> 24;
        int r = atomicAdd(&lrank[loc], 1);
        csr_src[base + lex[loc] + r] = (int)(p & 0xFFFFFFu);
    }
}

// C[M x NC](bf16) = dinv[row] * (A[M x 128] @ Wt^T). Wt is [NC x 128] bf16.
typedef __attribute__((ext_vector_type(8))) short bf16x8;
typedef __attribute__((ext_vector_type(4))) float f32x4;

template <int NC, bool A_BF16>
__global__ __launch_bounds__(256) void k_gemm_mfma(const void* __restrict__ Av,
                                                   const unsigned short* __restrict__ Wt,
                                                   const float* __restrict__ dinv,
                                                   unsigned short* __restrict__ Out, int M) {
    constexpr int KP = 136;                 // padded k-stride
    __shared__ __align__(16) short As[64 * KP];
    __shared__ __align__(16) short Bs[NC * KP];
    const int tid = threadIdx.x;
    const int row0 = blockIdx.x * 64;

    if (A_BF16) {
        const unsigned short* A = (const unsigned short*)Av;
#pragma unroll
        for (int q = 0; q < 4; q++) {
            int f = tid + 256 * q;
            int r = f >> 4, c = (f & 15) * 8;
            uint4 v = make_uint4(0, 0, 0, 0);
            if (row0 + r < M) v = *(const uint4*)&A[(size_t)(row0 + r) * 128 + c];
            *(uint4*)&As[r * KP + c] = v;
        }
    } else {
        const float* A = (const float*)Av;
#pragma unroll
        for (int q = 0; q < 8; q++) {
            int f = tid + 256 * q;
            int r = f >> 5, c = (f & 31) * 4;
            float4 v = make_float4(0.f, 0.f, 0.f, 0.f);
            if (row0 + r < M) v = *(const float4*)&A[(size_t)(row0 + r) * 128 + c];
            ushort4 o;
            o.x = f2bf(v.x); o.y = f2bf(v.y); o.z = f2bf(v.z); o.w = f2bf(v.w);
            *(ushort4*)&As[r * KP + c] = o;
        }
    }
    for (int f = tid; f < NC * 16; f += 256) {
        int n = f >> 4, c = (f & 15) * 8;
        *(uint4*)&Bs[n * KP + c] = *(const uint4*)&Wt[n * 128 + c];
    }
    __syncthreads();

    const int wave = tid >> 6, lane = tid & 63;
    const int m = lane & 15, quad = lane >> 4;
    constexpr int CT = NC / 16;
    f32x4 acc[CT] = {};
    const short* arow = &As[(16 * wave + m) * KP + quad * 8];
    const short* brow = &Bs[m * KP + quad * 8];
#pragma unroll
    for (int k0 = 0; k0 < 128; k0 += 32) {
        bf16x8 a = *(const bf16x8*)&arow[k0];
#pragma unroll
        for (int c = 0; c < CT; c++) {
            bf16x8 b = *(const bf16x8*)&brow[(size_t)c * 16 * KP + k0];
            acc[c] = __builtin_amdgcn_mfma_f32_16x16x32_bf16(a, b, acc[c], 0, 0, 0);
        }
    }

    // row-scale by dinv and repack through LDS for coalesced bf16 stores
    float dv[4];
#pragma unroll
    for (int r = 0; r < 4; r++) {
        int row = row0 + 16 * wave + quad * 4 + r;
        dv[r] = dinv[row < M ? row : (M - 1)];
    }
    __syncthreads();
    short* Cs = As;
#pragma unroll
    for (int c = 0; c < CT; c++)
#pragma unroll
        for (int r = 0; r < 4; r++)
            Cs[(16 * wave + quad * 4 + r) * NC + 16 * c + m] = (short)f2bf(acc[c][r] * dv[r]);
    __syncthreads();
    for (int f = tid; f < 64 * NC / 8; f += 256) {
        int r = f / (NC / 8), c = (f % (NC / 8)) * 8;
        if (row0 + r < M)
            *(uint4*)&Out[(size_t)(row0 + r) * NC + c] = *(const uint4*)&Cs[r * NC + c];
    }
}

// Aggregate 128-wide pre-scaled bf16 rows: one wave per node, unroll-8 gather-sum,
// then di*acc + bias, ReLU, bf16 store.
__global__ __launch_bounds__(256) void k_agg128b(const int* __restrict__ csr_src,
                                                 const int* __restrict__ rowptr,
                                                 const int* __restrict__ cnt,
                                                 const float* __restrict__ dinv,
                                                 const unsigned* __restrict__ xw,
                                                 const float* __restrict__ bias,
                                                 unsigned* __restrict__ h1, int N) {
    const int lane = threadIdx.x & 63;
    const int i = (blockIdx.x * blockDim.x + threadIdx.x) >> 6;
    if (i >= N) return;
    const float di = dinv[i];
    unsigned u = xw[(size_t)i * 64 + lane];          // self row (pre-scaled by dinv[i])
    float acc0 = bf_lo(u);
    float acc1 = bf_hi(u);
    const int start = rowptr[i], cn = cnt[i];
    int j = 0;
    for (; j + 8 <= cn; j += 8) {
        int s[8]; unsigned uu[8];
#pragma unroll
        for (int k = 0; k < 8; k++) s[k] = csr_src[start + j + k];   // wave-uniform -> s_load
#pragma unroll
        for (int k = 0; k < 8; k++) uu[k] = xw[(size_t)s[k] * 64 + lane];
#pragma unroll
        for (int k = 0; k < 8; k++) {
            acc0 += bf_lo(uu[k]);
            acc1 += bf_hi(uu[k]);
        }
    }
    for (; j < cn; j++) {
        int s0 = csr_src[start + j];
        unsigned u0 = xw[(size_t)s0 * 64 + lane];
        acc0 += bf_lo(u0); acc1 += bf_hi(u0);
    }
    float2 b = *(const float2*)&bias[2 * lane];
    float r0 = fmaxf(di * acc0 + b.x, 0.f);          // ReLU folded (layer-1 epilogue)
    float r1 = fmaxf(di * acc1 + b.y, 0.f);
    h1[(size_t)i * 64 + lane] = (unsigned)f2bf(r0) | ((unsigned)f2bf(r1) << 16);
}

// Aggregate 64-wide pre-scaled bf16 rows: HALF-WAVE per node (2 nodes/wave),
// contiguous unroll-8 edge walk (16 gathers in flight/wave), fused log_softmax.
__global__ __launch_bounds__(256) void k_agg64b(const int* __restrict__ csr_src,
                                                const int* __restrict__ rowptr,
                                                const int* __restrict__ cnt,
                                                const float* __restrict__ dinv,
                                                const unsigned* __restrict__ xw,
                                                const float* __restrict__ bias,
                                                float* __restrict__ out, int N) {
    const int sl = threadIdx.x & 31;                 // lane within half-wave
    const int i = blockIdx.x * 8 + (threadIdx.x >> 5);
    if (i >= N) return;
    const float di = dinv[i];
    unsigned u = xw[(size_t)i * 32 + sl];            // self row (pre-scaled)
    float acc0 = bf_lo(u), acc1 = bf_hi(u);
    const int start = rowptr[i], cn = cnt[i];
    int j = 0;
    for (; j + 8 <= cn; j += 8) {
        int s[8]; unsigned uu[8];
#pragma unroll
        for (int k = 0; k < 8; k++) s[k] = csr_src[start + j + k];
#pragma unroll
        for (int k = 0; k < 8; k++) uu[k] = xw[(size_t)s[k] * 32 + sl];
#pragma unroll
        for (int k = 0; k < 8; k++) {
            acc0 += bf_lo(uu[k]);
            acc1 += bf_hi(uu[k]);
        }
    }
    for (; j < cn; j++) {
        int s0 = csr_src[start + j];
        unsigned u0 = xw[(size_t)s0 * 32 + sl];
        acc0 += bf_lo(u0); acc1 += bf_hi(u0);
    }
    float2 b = *(const float2*)&bias[2 * sl];
    float v0 = di * acc0 + b.x, v1 = di * acc1 + b.y;
    // log_softmax over 64 cols held by this half-wave (2 per lane)
    float m = fmaxf(v0, v1);
#pragma unroll
    for (int o = 16; o > 0; o >>= 1) m = fmaxf(m, __shfl_xor(m, o));
    float s2 = expf(v0 - m) + expf(v1 - m);
#pragma unroll
    for (int o = 16; o > 0; o >>= 1) s2 += __shfl_xor(s2, o);
    float ls = m + logf(s2);
    *(float2*)&out[(size_t)i * 64 + 2 * sl] = make_float2(v0 - ls, v1 - ls);
}

extern "C" void kernel_launch(void* const* d_in, const int* in_sizes, int n_in,
                              void* d_out, int out_size, void* d_ws, size_t ws_size,
                              hipStream_t stream) {
    const float* x  = (const float*)d_in[0];
    const int*   ei = (const int*)d_in[1];
    const float* W1 = (const float*)d_in[2];
    const float* b1 = (const float*)d_in[3];
    const float* W2 = (const float*)d_in[4];
    const float* b2 = (const float*)d_in[5];

    const int N = in_sizes[0] / 128;   // 100000
    const int E = in_sizes[1] / 2;     // 1600000
    const int* src = ei;
    const int* dst = ei + E;
    const int B = (N + 255) >> BSHIFT;          // 391 buckets
    const int W = (E + CHUNK - 1) / CHUNK;      // 196 chunks

    char* ws = (char*)d_ws;
    size_t off = 0;
    auto alloc = [&](size_t bytes) {
        void* p = ws + off;
        off += (bytes + 255) & ~(size_t)255;
        return p;
    };
    int*            pcnt    = (int*)alloc((size_t)W * MAXB * 4);
    int*            coff    = (int*)alloc((size_t)W * MAXB * 4);
    int*            boff    = (int*)alloc((MAXB + 1) * 4);
    int*            deg     = (int*)alloc((size_t)N * 4);
    float*          dinv    = (float*)alloc((size_t)N * 4);
    int*            rowptr  = (int*)alloc((size_t)N * 4);
    int*            csr_src = (int*)alloc((size_t)E * 4);
    unsigned*       pairs   = (unsigned*)alloc((size_t)E * 4);
    unsigned short* Wt1     = (unsigned short*)alloc(128 * 128 * 2);
    unsigned short* Wt2     = (unsigned short*)alloc(64 * 128 * 2);
    unsigned short* xw1     = (unsigned short*)alloc((size_t)N * 128 * 2);  // bf16; reused as hw2
    unsigned short* h1      = (unsigned short*)alloc((size_t)N * 128 * 2);  // bf16
    unsigned short* hw2     = xw1;
    float*          out     = (float*)d_out;

    // CSR build (atomic-free front-end) + weight cast
    k_bcount<<<W, THREADS, 0, stream>>>(dst, E, pcnt);
    k_bscan<<<49, 512, 0, stream>>>(pcnt, W, coff, boff, W1, W2, Wt1, Wt2);
    k_bscatter<<<W, THREADS, 0, stream>>>(src, dst, E, boff, coff, pairs);
    k_bbuild<<<B, THREADS, 0, stream>>>(pairs, boff, N, deg, dinv, rowptr, csr_src);

    // Layer 1 (table pre-scaled by dinv[row] in the GEMM epilogue)
    k_gemm_mfma<128, false><<<(N + 63) / 64, THREADS, 0, stream>>>(x, Wt1, dinv, xw1, N);
    k_agg128b<<<(N * 64 + THREADS - 1) / THREADS, THREADS, 0, stream>>>(
        csr_src, rowptr, deg, dinv, (const unsigned*)xw1, b1, (unsigned*)h1, N);

    // Layer 2 (+ fused log_softmax in agg64b)
    k_gemm_mfma<64, true><<<(N + 63) / 64, THREADS, 0, stream>>>(h1, Wt2, dinv, hw2, N);
    k_agg64b<<<(N + 7) / 8, THREADS, 0, stream>>>(
        csr_src, rowptr, deg, dinv, (const unsigned*)hw2, b2, out, N);
}